// Round 2
// baseline (518.754 us; speedup 1.0000x reference)
//
#include <hip/hip_runtime.h>
#include <cstddef>
#include <stdint.h>

#define B_ 4
#define H_ 16
#define L_ 8192
#define D_ 64
#define BH_ 64

// 8192^(-0.25)
#define SCALE 0.1051120519067143f

__device__ __forceinline__ float elu1(float x) {
    return x > 0.0f ? (x + 1.0f) : __expf(x);
}
__device__ __forceinline__ unsigned short f2bf_rne(float x) {
    unsigned u = __float_as_uint(x);
    u += 0x7fffu + ((u >> 16) & 1u);
    return (unsigned short)(u >> 16);
}
__device__ __forceinline__ float bf_lo(unsigned w) { return __uint_as_float(w << 16); }
__device__ __forceinline__ float bf_hi(unsigned w) { return __uint_as_float(w & 0xffff0000u); }

// ---------------------------------------------------------------------------
// Zero the KV workspace: 64*64*64 floats = 65536 float4
// ---------------------------------------------------------------------------
__global__ __launch_bounds__(256) void zero_kernel(float4* __restrict__ p) {
    p[(size_t)blockIdx.x * 256 + threadIdx.x] = make_float4(0.f, 0.f, 0.f, 0.f);
}

// ---------------------------------------------------------------------------
// Phase 1: KV[bh][d][e] += sum_l Kf[l][d] * Vm[l][e]
// grid (64, 16), 256 threads. Wave-row-split 8x8 register tiles.
// Kf staged (transformed, mask^2-folded) in LDS; V read direct from global.
// ---------------------------------------------------------------------------
#define CH1 16
#define ROWS1 (L_ / CH1)   // 512 rows per block
#define TR1 64             // tile rows
#define SKLD 68            // padded LDS row stride (floats)

__global__ __launch_bounds__(256, 4) void kv_kernel(
    const float* __restrict__ K, const float* __restrict__ V,
    const float* __restrict__ mask, const float* __restrict__ pi,
    const float* __restrict__ mu, float* __restrict__ kv)
{
    __shared__ float sK[TR1 * SKLD];   // 4352 floats; reused as red[4096]
    __shared__ float muc[64];

    const int bh = blockIdx.x;
    const int b  = bh >> 4;
    const int h  = bh & 15;
    const int l0 = blockIdx.y * ROWS1;
    const int t  = threadIdx.x;
    const int wave = t >> 6;
    const int lane = t & 63;
    const int d0 = (lane >> 3) * 8;
    const int e0 = (lane & 7) * 8;

    const float p0 = fminf(fmaxf(pi[0], 0.f), 1.f);
    const float p1 = fminf(fmaxf(pi[1], 0.f), 1.f);
    const float psum = p0 + p1;
    if (t < 64) muc[t] = p0 * mu[h * 64 + t] + p1 * mu[1024 + h * 64 + t];

    const float* Kb = K + (size_t)bh * (L_ * 64);
    const float* Vb = V + (size_t)bh * (L_ * 64);
    const float* mb = mask + (size_t)b * L_;

    const int trow = t >> 2;            // 0..63
    const int tc   = (t & 3) * 16;      // 0,16,32,48

    float acc[64];
#pragma unroll
    for (int i = 0; i < 64; ++i) acc[i] = 0.f;

#pragma unroll 1
    for (int tile = 0; tile < ROWS1; tile += TR1) {
        const int base = l0 + tile;
        __syncthreads();
        // stage 64 transformed K rows: Kf = elu1(K*psum - muc) * s * m^2
        {
            const int row = base + trow;
            const float m = mb[row];
            const float sm2 = SCALE * m * m;
            const float* kp = Kb + (size_t)row * 64 + tc;
#pragma unroll
            for (int q = 0; q < 4; ++q) {
                float4 kk = *(const float4*)(kp + 4 * q);
                float4 mm = *(const float4*)(&muc[tc + 4 * q]);
                float4 o;
                o.x = elu1(kk.x * psum - mm.x) * sm2;
                o.y = elu1(kk.y * psum - mm.y) * sm2;
                o.z = elu1(kk.z * psum - mm.z) * sm2;
                o.w = elu1(kk.w * psum - mm.w) * sm2;
                *(float4*)&sK[trow * SKLD + tc + 4 * q] = o;
            }
        }
        __syncthreads();
        // each wave: 16 rows (stride 4), 64 FMA per row
#pragma unroll
        for (int j = 0; j < 16; ++j) {
            const int r = wave + 4 * j;
            const float* vp = Vb + (size_t)(base + r) * 64 + e0;
            const float4 va = *(const float4*)(vp);
            const float4 vb = *(const float4*)(vp + 4);
            const float4 ka = *(const float4*)&sK[r * SKLD + d0];
            const float4 kb = *(const float4*)&sK[r * SKLD + d0 + 4];
            const float kf[8] = {ka.x, ka.y, ka.z, ka.w, kb.x, kb.y, kb.z, kb.w};
            const float vf[8] = {va.x, va.y, va.z, va.w, vb.x, vb.y, vb.z, vb.w};
#pragma unroll
            for (int i = 0; i < 8; ++i)
#pragma unroll
                for (int jj = 0; jj < 8; ++jj)
                    acc[i * 8 + jj] = fmaf(kf[i], vf[jj], acc[i * 8 + jj]);
        }
    }

    // block-level reduction of the 4 per-wave partial 64x64 tiles (reuse sK)
    __syncthreads();
    float* red = sK;
#pragma unroll 1
    for (int w = 0; w < 4; ++w) {
        if (wave == w) {
#pragma unroll
            for (int i = 0; i < 8; ++i)
#pragma unroll
                for (int jj = 0; jj < 8; ++jj) {
                    const int idx = (d0 + i) * 64 + e0 + jj;
                    red[idx] = (w == 0) ? acc[i * 8 + jj] : red[idx] + acc[i * 8 + jj];
                }
        }
        __syncthreads();
    }

    float* kvb = kv + (size_t)bh * 4096;
#pragma unroll
    for (int k = 0; k < 16; ++k)
        atomicAdd(kvb + k * 256 + t, red[k * 256 + t]);
}

// ---------------------------------------------------------------------------
// Phase 2: out[l][e] = sum_d Qf[l][d] * KV[d][e]
// grid (64, 32), 256 threads. Per-wave 64-row subtile, 8x8 register tiles.
// Qf (transposed) and KV staged as bf16 in LDS -> 8 b128 per 256 FMA.
// ---------------------------------------------------------------------------
#define ROWS2 256

__global__ __launch_bounds__(256, 3) void out_kernel(
    const float* __restrict__ Q, const float* __restrict__ kv,
    float* __restrict__ out)
{
    __shared__ unsigned short skv[64 * 64];        // bf16 KV, 8 KB
    __shared__ unsigned short sqt[4][64 * 64];     // per-wave bf16 Q^T, 32 KB

    const int bh = blockIdx.x;
    const int l0 = blockIdx.y * ROWS2;
    const int t = threadIdx.x;
    const int wave = t >> 6;
    const int lane = t & 63;
    const int r0 = (lane >> 3) * 8;
    const int e0 = (lane & 7) * 8;

    // coop load KV -> bf16 LDS (16 floats per thread)
    {
        const float* kvb = kv + (size_t)bh * 4096 + t * 16;
        unsigned w[8];
#pragma unroll
        for (int q = 0; q < 4; ++q) {
            float4 f = *(const float4*)(kvb + 4 * q);
            w[2 * q + 0] = (unsigned)f2bf_rne(f.x) | ((unsigned)f2bf_rne(f.y) << 16);
            w[2 * q + 1] = (unsigned)f2bf_rne(f.z) | ((unsigned)f2bf_rne(f.w) << 16);
        }
        *(uint4*)&skv[t * 16 + 0] = make_uint4(w[0], w[1], w[2], w[3]);
        *(uint4*)&skv[t * 16 + 8] = make_uint4(w[4], w[5], w[6], w[7]);
    }
    // stage Q^T for this wave's 64-row subtile: lane = row
    {
        const int row = l0 + wave * 64 + lane;
        const float* qp = Q + (size_t)bh * (L_ * 64) + (size_t)row * 64;
        unsigned short* qt = &sqt[wave][0];
#pragma unroll
        for (int c4 = 0; c4 < 16; ++c4) {
            float4 q = *(const float4*)(qp + 4 * c4);
            qt[(4 * c4 + 0) * 64 + lane] = f2bf_rne(elu1(q.x) * SCALE);
            qt[(4 * c4 + 1) * 64 + lane] = f2bf_rne(elu1(q.y) * SCALE);
            qt[(4 * c4 + 2) * 64 + lane] = f2bf_rne(elu1(q.z) * SCALE);
            qt[(4 * c4 + 3) * 64 + lane] = f2bf_rne(elu1(q.w) * SCALE);
        }
    }
    __syncthreads();

    float acc[64];
#pragma unroll
    for (int i = 0; i < 64; ++i) acc[i] = 0.f;

    const unsigned short* qt = &sqt[wave][0];
#pragma unroll 1
    for (int c = 0; c < 16; ++c) {
#pragma unroll
        for (int k = 0; k < 4; ++k) {
            const int d = 4 * c + k;
            const uint4 qw = *(const uint4*)&qt[d * 64 + r0];
            const uint4 kw = *(const uint4*)&skv[d * 64 + e0];
            const float qf[8] = {bf_lo(qw.x), bf_hi(qw.x), bf_lo(qw.y), bf_hi(qw.y),
                                 bf_lo(qw.z), bf_hi(qw.z), bf_lo(qw.w), bf_hi(qw.w)};
            const float kf[8] = {bf_lo(kw.x), bf_hi(kw.x), bf_lo(kw.y), bf_hi(kw.y),
                                 bf_lo(kw.z), bf_hi(kw.z), bf_lo(kw.w), bf_hi(kw.w)};
#pragma unroll
            for (int i = 0; i < 8; ++i)
#pragma unroll
                for (int j = 0; j < 8; ++j)
                    acc[i * 8 + j] = fmaf(qf[i], kf[j], acc[i * 8 + j]);
        }
    }

    float* ob = out + (size_t)bh * (L_ * 64) + (size_t)(l0 + wave * 64 + r0) * 64 + e0;
#pragma unroll
    for (int i = 0; i < 8; ++i) {
        float4 oa, obv;
        oa.x = acc[i * 8 + 0]; oa.y = acc[i * 8 + 1];
        oa.z = acc[i * 8 + 2]; oa.w = acc[i * 8 + 3];
        obv.x = acc[i * 8 + 4]; obv.y = acc[i * 8 + 5];
        obv.z = acc[i * 8 + 6]; obv.w = acc[i * 8 + 7];
        *(float4*)(ob + (size_t)i * 64) = oa;
        *(float4*)(ob + (size_t)i * 64 + 4) = obv;
    }
}

extern "C" void kernel_launch(void* const* d_in, const int* in_sizes, int n_in,
                              void* d_out, int out_size, void* d_ws, size_t ws_size,
                              hipStream_t stream) {
    (void)in_sizes; (void)n_in; (void)out_size; (void)ws_size;
    const float* Q    = (const float*)d_in[0];
    const float* K    = (const float*)d_in[1];
    const float* V    = (const float*)d_in[2];
    const float* mask = (const float*)d_in[3];
    const float* pi   = (const float*)d_in[4];
    const float* mu   = (const float*)d_in[5];
    float* out = (float*)d_out;
    float* kvw = (float*)d_ws;   // 64*64*64 floats = 1 MiB

    zero_kernel<<<256, 256, 0, stream>>>((float4*)kvw);
    kv_kernel<<<dim3(BH_, CH1), 256, 0, stream>>>(K, V, mask, pi, mu, kvw);
    out_kernel<<<dim3(BH_, L_ / ROWS2), 256, 0, stream>>>(Q, kvw, out);
}

// Round 3
// 419.089 us; speedup vs baseline: 1.2378x; 1.2378x over previous
//
#include <hip/hip_runtime.h>
#include <cstddef>
#include <stdint.h>

#define L_ 8192
#define BH_ 64
#define SCALE 0.1051120519067143f
#define SLD 72   // LDS row stride in ushorts (144 B -> 4-bank rotation, <=2-way)

typedef __attribute__((ext_vector_type(8))) short bf16x8;
typedef __attribute__((ext_vector_type(4))) float f32x4;

__device__ __forceinline__ float elu1(float x) {
    return x > 0.0f ? (x + 1.0f) : __expf(x);
}
__device__ __forceinline__ unsigned short f2bf(float x) {
    unsigned u = __float_as_uint(x);
    u += 0x7fffu + ((u >> 16) & 1u);
    return (unsigned short)(u >> 16);
}

// ---------------------------------------------------------------------------
// Zero the KV workspace: 64*64*64 floats = 65536 float4
// ---------------------------------------------------------------------------
__global__ __launch_bounds__(256) void zero_kernel(float4* __restrict__ p) {
    p[(size_t)blockIdx.x * 256 + threadIdx.x] = make_float4(0.f, 0.f, 0.f, 0.f);
}

// ---------------------------------------------------------------------------
// Phase 1: KV[d][e] += sum_l Kf[l][d] * Vm[l][e]  ==  (Kf^T)(64xL) x Vm(Lx64)
// grid (64, 32), 256 thr. Per 64-l tile: stage Kf^T, Vm^T as bf16 in LDS,
// wave w computes C rows d in [16w,16w+16) x all e via 8 MFMA.
// ---------------------------------------------------------------------------
__global__ __launch_bounds__(256) void kv_kernel(
    const float* __restrict__ K, const float* __restrict__ V,
    const float* __restrict__ mask, const float* __restrict__ pi,
    const float* __restrict__ mu, float* __restrict__ kv)
{
    __shared__ __align__(16) unsigned short sKt[64 * SLD];  // [d][l] bf16
    __shared__ __align__(16) unsigned short sVt[64 * SLD];  // [e][l] bf16
    __shared__ float muc[64];

    const int bh = blockIdx.x;
    const int b  = bh >> 4;
    const int h  = bh & 15;
    const int l0 = blockIdx.y * 256;
    const int t    = threadIdx.x;
    const int wave = t >> 6;
    const int lane = t & 63;
    const int r = lane & 15;      // MFMA m/n index
    const int q = lane >> 4;      // MFMA quad

    const float p0 = fminf(fmaxf(pi[0], 0.f), 1.f);
    const float p1 = fminf(fmaxf(pi[1], 0.f), 1.f);
    const float psum = p0 + p1;
    if (t < 64) muc[t] = p0 * mu[h * 64 + t] + p1 * mu[1024 + h * 64 + t];

    const float* Kb = K + (size_t)bh * (L_ * 64);
    const float* Vb = V + (size_t)bh * (L_ * 64);
    const float* mb = mask + (size_t)b * L_;

    const int lloc = t >> 2;      // 0..63: tile-local l row this thread stages
    const int cb   = t & 3;       // column-chunk base

    f32x4 acc[4];
#pragma unroll
    for (int i = 0; i < 4; ++i) acc[i] = (f32x4){0.f, 0.f, 0.f, 0.f};

    __syncthreads();   // muc visible

#pragma unroll 1
    for (int tile = 0; tile < 4; ++tile) {
        const int lrow = l0 + tile * 64 + lloc;
        const float m = mb[lrow];
        const float sm2 = SCALE * m * m;    // fold mask^2 * s into Kf; V stays raw
        const float* kp = Kb + (size_t)lrow * 64;
        const float* vp = Vb + (size_t)lrow * 64;
        if (tile) __syncthreads();
#pragma unroll
        for (int i = 0; i < 4; ++i) {
            const int c4 = cb + 4 * i;      // chunk of 4 columns
            const float4 kk = *(const float4*)(kp + 4 * c4);
            const float4 mm = *(const float4*)(&muc[4 * c4]);
            sKt[(4 * c4 + 0) * SLD + lloc] = f2bf(elu1(kk.x * psum - mm.x) * sm2);
            sKt[(4 * c4 + 1) * SLD + lloc] = f2bf(elu1(kk.y * psum - mm.y) * sm2);
            sKt[(4 * c4 + 2) * SLD + lloc] = f2bf(elu1(kk.z * psum - mm.z) * sm2);
            sKt[(4 * c4 + 3) * SLD + lloc] = f2bf(elu1(kk.w * psum - mm.w) * sm2);
            const float4 vv = *(const float4*)(vp + 4 * c4);
            sVt[(4 * c4 + 0) * SLD + lloc] = f2bf(vv.x);
            sVt[(4 * c4 + 1) * SLD + lloc] = f2bf(vv.y);
            sVt[(4 * c4 + 2) * SLD + lloc] = f2bf(vv.z);
            sVt[(4 * c4 + 3) * SLD + lloc] = f2bf(vv.w);
        }
        __syncthreads();

        // A frags: Kf^T[m=16w+r][k=32ks+8q+j]
        const bf16x8 a0 = *(const bf16x8*)&sKt[(16 * wave + r) * SLD + 8 * q];
        const bf16x8 a1 = *(const bf16x8*)&sKt[(16 * wave + r) * SLD + 32 + 8 * q];
#pragma unroll
        for (int nt = 0; nt < 4; ++nt) {
            const bf16x8 b0 = *(const bf16x8*)&sVt[(16 * nt + r) * SLD + 8 * q];
            const bf16x8 b1 = *(const bf16x8*)&sVt[(16 * nt + r) * SLD + 32 + 8 * q];
            acc[nt] = __builtin_amdgcn_mfma_f32_16x16x32_bf16(a0, b0, acc[nt], 0, 0, 0);
            acc[nt] = __builtin_amdgcn_mfma_f32_16x16x32_bf16(a1, b1, acc[nt], 0, 0, 0);
        }
    }

    float* kvb = kv + (size_t)bh * 4096;
#pragma unroll
    for (int nt = 0; nt < 4; ++nt)
#pragma unroll
        for (int reg = 0; reg < 4; ++reg)
            atomicAdd(kvb + (16 * wave + 4 * q + reg) * 64 + 16 * nt + r, acc[nt][reg]);
}

// ---------------------------------------------------------------------------
// Phase 2: out = Qf(Lx64) x KV(64x64) per bh.
// grid (64, 16), 256 thr. KV^T staged once as bf16, whole B held in 32 VGPRs.
// A-frags loaded straight from global Q (coalesced), prefetched one tile ahead.
// ---------------------------------------------------------------------------
__global__ __launch_bounds__(256) void out_kernel(
    const float* __restrict__ Q, const float* __restrict__ kv,
    float* __restrict__ out)
{
    __shared__ __align__(16) unsigned short sKVt[64 * SLD];  // [e][d] bf16

    const int bh = blockIdx.x;
    const int l0 = blockIdx.y * 512;
    const int t    = threadIdx.x;
    const int wave = t >> 6;
    const int lane = t & 63;
    const int r = lane & 15;
    const int q = lane >> 4;

    // stage KV transposed -> bf16 (one time)
    {
        const float* kvb = kv + (size_t)bh * 4096 + t * 16;
        const int d  = t >> 2;
        const int e0 = (t & 3) * 16;
#pragma unroll
        for (int j4 = 0; j4 < 4; ++j4) {
            const float4 f = *(const float4*)(kvb + 4 * j4);
            sKVt[(e0 + 4 * j4 + 0) * SLD + d] = f2bf(f.x);
            sKVt[(e0 + 4 * j4 + 1) * SLD + d] = f2bf(f.y);
            sKVt[(e0 + 4 * j4 + 2) * SLD + d] = f2bf(f.z);
            sKVt[(e0 + 4 * j4 + 3) * SLD + d] = f2bf(f.w);
        }
    }
    __syncthreads();

    // whole B operand in registers: B[k=d][n=e], frag = KV^T[16nt+r][32ks+8q+j]
    bf16x8 bfr[4][2];
#pragma unroll
    for (int nt = 0; nt < 4; ++nt) {
        bfr[nt][0] = *(const bf16x8*)&sKVt[(16 * nt + r) * SLD + 8 * q];
        bfr[nt][1] = *(const bf16x8*)&sKVt[(16 * nt + r) * SLD + 32 + 8 * q];
    }

    const int mbase = l0 + wave * 128;   // this wave's 128 rows
    const float* qrow = Q + (size_t)bh * (L_ * 64) + (size_t)(mbase + r) * 64 + 8 * q;
    float* ob = out + (size_t)bh * (L_ * 64);

    float4 c0 = *(const float4*)(qrow);
    float4 c1 = *(const float4*)(qrow + 4);
    float4 c2 = *(const float4*)(qrow + 32);
    float4 c3 = *(const float4*)(qrow + 36);

#pragma unroll 1
    for (int mt = 0; mt < 8; ++mt) {
        float4 n0, n1, n2, n3;
        if (mt < 7) {
            const float* nq = qrow + (size_t)(mt + 1) * 16 * 64;
            n0 = *(const float4*)(nq);
            n1 = *(const float4*)(nq + 4);
            n2 = *(const float4*)(nq + 32);
            n3 = *(const float4*)(nq + 36);
        }
        bf16x8 a0, a1;
        a0[0] = f2bf(elu1(c0.x) * SCALE); a0[1] = f2bf(elu1(c0.y) * SCALE);
        a0[2] = f2bf(elu1(c0.z) * SCALE); a0[3] = f2bf(elu1(c0.w) * SCALE);
        a0[4] = f2bf(elu1(c1.x) * SCALE); a0[5] = f2bf(elu1(c1.y) * SCALE);
        a0[6] = f2bf(elu1(c1.z) * SCALE); a0[7] = f2bf(elu1(c1.w) * SCALE);
        a1[0] = f2bf(elu1(c2.x) * SCALE); a1[1] = f2bf(elu1(c2.y) * SCALE);
        a1[2] = f2bf(elu1(c2.z) * SCALE); a1[3] = f2bf(elu1(c2.w) * SCALE);
        a1[4] = f2bf(elu1(c3.x) * SCALE); a1[5] = f2bf(elu1(c3.y) * SCALE);
        a1[6] = f2bf(elu1(c3.z) * SCALE); a1[7] = f2bf(elu1(c3.w) * SCALE);

        f32x4 acc[4];
#pragma unroll
        for (int nt = 0; nt < 4; ++nt) {
            acc[nt] = (f32x4){0.f, 0.f, 0.f, 0.f};
            acc[nt] = __builtin_amdgcn_mfma_f32_16x16x32_bf16(a0, bfr[nt][0], acc[nt], 0, 0, 0);
            acc[nt] = __builtin_amdgcn_mfma_f32_16x16x32_bf16(a1, bfr[nt][1], acc[nt], 0, 0, 0);
        }

        float* orow = ob + (size_t)(mbase + mt * 16 + 4 * q) * 64;
#pragma unroll
        for (int nt = 0; nt < 4; ++nt)
#pragma unroll
            for (int reg = 0; reg < 4; ++reg)
                orow[(size_t)reg * 64 + 16 * nt + r] = acc[nt][reg];

        c0 = n0; c1 = n1; c2 = n2; c3 = n3;
    }
}

extern "C" void kernel_launch(void* const* d_in, const int* in_sizes, int n_in,
                              void* d_out, int out_size, void* d_ws, size_t ws_size,
                              hipStream_t stream) {
    (void)in_sizes; (void)n_in; (void)out_size; (void)ws_size;
    const float* Q    = (const float*)d_in[0];
    const float* K    = (const float*)d_in[1];
    const float* V    = (const float*)d_in[2];
    const float* mask = (const float*)d_in[3];
    const float* pi   = (const float*)d_in[4];
    const float* mu   = (const float*)d_in[5];
    float* out = (float*)d_out;
    float* kvw = (float*)d_ws;   // 64*64*64 floats = 1 MiB

    zero_kernel<<<256, 256, 0, stream>>>((float4*)kvw);
    kv_kernel<<<dim3(BH_, 32), 256, 0, stream>>>(K, V, mask, pi, mu, kvw);
    out_kernel<<<dim3(BH_, 16), 256, 0, stream>>>(Q, kvw, out);
}